// Round 3
// baseline (804.925 us; speedup 1.0000x reference)
//
#include <hip/hip_runtime.h>
#include <stdint.h>

// Problem (fp32 in / fp32 out): out = relu((x + (x@Wv^T+bv)@Wo^T + bo) @ Wn^T + bn)
//   softmax over a single score == 1 -> q,k path is dead code.
// Reformulated: out = relu(x@Wn^T + v@Wm^T + biasTot)
//   v  = x@Wv^T + bv          [8192 x 64]
//   Wm = Wn @ Wo              [4096 x 64]   (fp32 VALU, tiny)
//   biasTot = bn + Wn @ bo    [4096]
// Round 3: all prep fused into ONE kernel (k_pre) with independent block
// classes reading fp32 inputs; x and its bf16 conversion read/written once.

typedef unsigned short u16;
typedef float f32x4 __attribute__((ext_vector_type(4)));
typedef __bf16 bf16x8 __attribute__((ext_vector_type(8)));
typedef u16 u16x8 __attribute__((ext_vector_type(8)));

__device__ __forceinline__ float b2f(u16 u) {
  union { unsigned int i; float f; } x; x.i = ((unsigned int)u) << 16; return x.f;
}
__device__ __forceinline__ u16 f2b(float f) {  // round-to-nearest-even
  union { float f; unsigned int i; } x; x.f = f;
  unsigned int r = x.i + 0x7FFFu + ((x.i >> 16) & 1u);
  return (u16)(r >> 16);
}

// async global->LDS, 16B per lane; lds base wave-uniform (lane lands at base + lane*16B)
__device__ __forceinline__ void gl_lds16(const u16* g, u16* l) {
#if __has_builtin(__builtin_amdgcn_global_load_lds)
  __builtin_amdgcn_global_load_lds((__attribute__((address_space(1))) void*)g,
                                   (__attribute__((address_space(3))) void*)l, 16, 0, 0);
#else
  int lane = threadIdx.x & 63;
  *(u16x8*)(l + lane * 8) = *(const u16x8*)g;
#endif
}

__device__ __forceinline__ f32x4 mfma16(bf16x8 a, bf16x8 b, f32x4 c) {
  return __builtin_amdgcn_mfma_f32_16x16x32_bf16(a, b, c, 0, 0, 0);
}

// ---------------------------------------------------------------------------
// k_pre — fused prep. Block classes:
//   [0,256):    V-class: 32 x-rows -> xb (bf16) + V-tile (MFMA vs Wv)
//   [256,768):  Wm-class: 8 Wn-rows -> Wm + biasTot (fp32 VALU)
//   [768,8960): cvt-class: Wn -> Wnb (8 floats/thread)
// ---------------------------------------------------------------------------
#define LDAP 136  // bf16 LDS row stride (272 B, 16B-aligned, 2-way bank alias = free)
__global__ __launch_bounds__(256, 2) void k_pre(
    const float* __restrict__ x, const float* __restrict__ Wv, const float* __restrict__ bv,
    const float* __restrict__ Wo, const float* __restrict__ bo,
    const float* __restrict__ Wn, const float* __restrict__ bn,
    u16* __restrict__ xb, u16* __restrict__ Wnb,
    u16* __restrict__ V, u16* __restrict__ Wm, float* __restrict__ biasTot) {
  __shared__ __align__(16) u16 smem[32 * LDAP + 64 * LDAP];  // 26112 B
  const int bid = blockIdx.x;
  const int tid = threadIdx.x;

  if (bid >= 768) {  // ---- cvt-class: Wn -> Wnb ----
    long off = ((long)(bid - 768) * 256 + tid) * 8;
    f32x4 a = *(const f32x4*)&Wn[off];
    f32x4 b = *(const f32x4*)&Wn[off + 4];
    u16x8 o;
#pragma unroll
    for (int e = 0; e < 4; ++e) { o[e] = f2b(a[e]); o[4 + e] = f2b(b[e]); }
    *(u16x8*)&Wnb[off] = o;
    return;
  }

  if (bid >= 256) {  // ---- Wm-class: fp32 VALU, 8 rows/block, 2 rows/thread ----
    const long m0 = (long)(bid - 256) * 8;
    const int r = tid >> 6, a = tid & 63;
    const long row0 = m0 + r, row1 = m0 + 4 + r;
    const float* wn0p = &Wn[row0 * 4096];
    const float* wn1p = &Wn[row1 * 4096];
    float acc0 = 0.f, acc1 = 0.f;
    for (int k0 = 0; k0 < 4096; k0 += 8) {
      f32x4 a0 = *(const f32x4*)&wn0p[k0];
      f32x4 a1 = *(const f32x4*)&wn0p[k0 + 4];
      f32x4 b0 = *(const f32x4*)&wn1p[k0];
      f32x4 b1 = *(const f32x4*)&wn1p[k0 + 4];
      float wo[8];
#pragma unroll
      for (int j = 0; j < 8; ++j) wo[j] = Wo[(long)(k0 + j) * 64 + a];
#pragma unroll
      for (int j = 0; j < 4; ++j) { acc0 += a0[j] * wo[j]; acc1 += b0[j] * wo[j]; }
#pragma unroll
      for (int j = 0; j < 4; ++j) { acc0 += a1[j] * wo[4 + j]; acc1 += b1[j] * wo[4 + j]; }
    }
    Wm[row0 * 64 + a] = f2b(acc0);
    Wm[row1 * 64 + a] = f2b(acc1);
    // biasTot = bn + Wn . bo  (per-lane strided partials, wave reduce)
    float p0 = 0.f, p1 = 0.f;
#pragma unroll 4
    for (int j = 0; j < 64; ++j) {
      float bb = bo[j * 64 + a];
      p0 += wn0p[j * 64 + a] * bb;
      p1 += wn1p[j * 64 + a] * bb;
    }
#pragma unroll
    for (int o = 32; o > 0; o >>= 1) { p0 += __shfl_xor(p0, o, 64); p1 += __shfl_xor(p1, o, 64); }
    if (a == 0) { biasTot[row0] = p0 + bn[row0]; biasTot[row1] = p1 + bn[row1]; }
    return;
  }

  // ---- V-class: x rows [m0, m0+32): convert -> xb, and V = x@Wv^T + bv ----
  const int w = tid >> 6, l = tid & 63;
  u16* lA = smem;               // [32][LDAP] bf16 x-tile
  u16* lB = smem + 32 * LDAP;   // [64][LDAP] bf16 Wv-tile
  const long m0 = (long)bid * 32;
  const int mt = (w & 1) * 16, nb = (w >> 1) * 32;
  f32x4 acc[2];
  acc[0] = (f32x4)(0.f); acc[1] = (f32x4)(0.f);

  for (int k0 = 0; k0 < 4096; k0 += 128) {
    __syncthreads();
    {  // stage A: x[m0..+32][k0..+128], convert, write xb + lA
      int row = tid >> 3, c0 = (tid & 7) * 16;
      const float* s = &x[(m0 + row) * 4096 + k0 + c0];
      u16* gxb = &xb[(m0 + row) * 4096 + k0 + c0];
#pragma unroll
      for (int q = 0; q < 2; ++q) {
        f32x4 v0 = *(const f32x4*)&s[q * 8];
        f32x4 v1 = *(const f32x4*)&s[q * 8 + 4];
        u16x8 o;
#pragma unroll
        for (int e = 0; e < 4; ++e) { o[e] = f2b(v0[e]); o[4 + e] = f2b(v1[e]); }
        *(u16x8*)&lA[row * LDAP + c0 + q * 8] = o;
        *(u16x8*)&gxb[q * 8] = o;
      }
    }
    {  // stage B: Wv[0..64][k0..+128], convert -> lB
      int row = tid >> 2, c0 = (tid & 3) * 32;
      const float* s = &Wv[(long)row * 4096 + k0 + c0];
#pragma unroll
      for (int q = 0; q < 4; ++q) {
        f32x4 v0 = *(const f32x4*)&s[q * 8];
        f32x4 v1 = *(const f32x4*)&s[q * 8 + 4];
        u16x8 o;
#pragma unroll
        for (int e = 0; e < 4; ++e) { o[e] = f2b(v0[e]); o[4 + e] = f2b(v1[e]); }
        *(u16x8*)&lB[row * LDAP + c0 + q * 8] = o;
      }
    }
    __syncthreads();
#pragma unroll
    for (int kk = 0; kk < 4; ++kk) {
      int ko = kk * 32 + (l >> 4) * 8;
      bf16x8 af = *(const bf16x8*)&lA[(mt + (l & 15)) * LDAP + ko];
#pragma unroll
      for (int nt = 0; nt < 2; ++nt) {
        bf16x8 bf = *(const bf16x8*)&lB[(nb + nt * 16 + (l & 15)) * LDAP + ko];
        acc[nt] = mfma16(af, bf, acc[nt]);
      }
    }
  }
  // epilogue: V = acc + bv, bf16 scattered stores (tiny)
#pragma unroll
  for (int nt = 0; nt < 2; ++nt) {
    int col = nb + nt * 16 + (l & 15);
    float bb = bv[col];
#pragma unroll
    for (int r2 = 0; r2 < 4; ++r2) {
      long row = m0 + mt + (l >> 4) * 4 + r2;
      V[row * 64 + col] = f2b(acc[nt][r2] + bb);
    }
  }
}

// ---------------------------------------------------------------------------
// k_main: out = relu(xb@Wnb^T + V@Wm^T + biasTot) — UNCHANGED from round 2
//   (m97 structure: 128x128 tile, BK=32, global_load_lds(16B), K tail = 64,
//    fp32 out via per-wave LDS transpose -> dwordx4 stores)
// ---------------------------------------------------------------------------
__global__ __launch_bounds__(256, 2) void k_main(
    const u16* __restrict__ X, const u16* __restrict__ Wn,
    const u16* __restrict__ V, const u16* __restrict__ Wm,
    const float* __restrict__ biasTot, float* __restrict__ Out) {
  __shared__ __align__(16) u16 smem[2 * 128 * 32];  // 16 KB
  u16* lA = smem;
  u16* lB = smem + 128 * 32;
  const int tid = threadIdx.x;
  const int w = tid >> 6, l = tid & 63;
  const int wRow = (w & 1) * 64, wCol = (w >> 1) * 64;
  const long mBase = (long)(blockIdx.x >> 5) * 128;
  const int nBase = (int)(blockIdx.x & 31) * 128;

  f32x4 acc[4][4];
#pragma unroll
  for (int mt = 0; mt < 4; ++mt)
#pragma unroll
    for (int nt = 0; nt < 4; ++nt) acc[mt][nt] = (f32x4)(0.f);

  const int rl = l >> 2;
  const int kp = (l & 3) * 8;

  for (int k0 = 0; k0 < 4096; k0 += 32) {
    __syncthreads();
#pragma unroll
    for (int i = 0; i < 2; ++i) {
      int row = w * 32 + i * 16 + rl;
      gl_lds16(X + (mBase + row) * (long)4096 + k0 + kp, lA + (w * 32 + i * 16) * 32);
      gl_lds16(Wn + (long)(nBase + row) * 4096 + k0 + kp, lB + (w * 32 + i * 16) * 32);
    }
    __syncthreads();
    bf16x8 af[4], bfr[4];
#pragma unroll
    for (int mt = 0; mt < 4; ++mt)
      af[mt] = *(const bf16x8*)&lA[(wRow + mt * 16 + (l & 15)) * 32 + (l >> 4) * 8];
#pragma unroll
    for (int nt = 0; nt < 4; ++nt)
      bfr[nt] = *(const bf16x8*)&lB[(wCol + nt * 16 + (l & 15)) * 32 + (l >> 4) * 8];
#pragma unroll
    for (int mt = 0; mt < 4; ++mt)
#pragma unroll
      for (int nt = 0; nt < 4; ++nt) acc[mt][nt] = mfma16(af[mt], bfr[nt], acc[mt][nt]);
  }

  for (int k0 = 0; k0 < 64; k0 += 32) {
    __syncthreads();
#pragma unroll
    for (int i = 0; i < 2; ++i) {
      int row = w * 32 + i * 16 + rl;
      gl_lds16(V + (mBase + row) * (long)64 + k0 + kp, lA + (w * 32 + i * 16) * 32);
      gl_lds16(Wm + (long)(nBase + row) * 64 + k0 + kp, lB + (w * 32 + i * 16) * 32);
    }
    __syncthreads();
    bf16x8 af[4], bfr[4];
#pragma unroll
    for (int mt = 0; mt < 4; ++mt)
      af[mt] = *(const bf16x8*)&lA[(wRow + mt * 16 + (l & 15)) * 32 + (l >> 4) * 8];
#pragma unroll
    for (int nt = 0; nt < 4; ++nt)
      bfr[nt] = *(const bf16x8*)&lB[(wCol + nt * 16 + (l & 15)) * 32 + (l >> 4) * 8];
#pragma unroll
    for (int mt = 0; mt < 4; ++mt)
#pragma unroll
      for (int nt = 0; nt < 4; ++nt) acc[mt][nt] = mfma16(af[mt], bfr[nt], acc[mt][nt]);
  }

  __syncthreads();
  float* eb = ((float*)smem) + w * 1024;
#pragma unroll
  for (int mt = 0; mt < 4; ++mt) {
#pragma unroll
    for (int nt = 0; nt < 4; ++nt) {
      float bt = biasTot[nBase + wCol + nt * 16 + (l & 15)];
#pragma unroll
      for (int r = 0; r < 4; ++r) {
        float val = acc[mt][nt][r] + bt;
        eb[((l >> 4) * 4 + r) * 64 + nt * 16 + (l & 15)] = fmaxf(val, 0.f);
      }
    }
    int rr = l >> 2, c0 = (l & 3) * 16;
    long grow = mBase + wRow + mt * 16 + rr;
    int gcol = nBase + wCol + c0;
    f32x4 o0 = *(const f32x4*)&eb[rr * 64 + c0];
    f32x4 o1 = *(const f32x4*)&eb[rr * 64 + c0 + 4];
    f32x4 o2 = *(const f32x4*)&eb[rr * 64 + c0 + 8];
    f32x4 o3 = *(const f32x4*)&eb[rr * 64 + c0 + 12];
    *(f32x4*)&Out[grow * 4096 + gcol] = o0;
    *(f32x4*)&Out[grow * 4096 + gcol + 4] = o1;
    *(f32x4*)&Out[grow * 4096 + gcol + 8] = o2;
    *(f32x4*)&Out[grow * 4096 + gcol + 12] = o3;
  }
}

// ---------------------------------------------------------------------------
extern "C" void kernel_launch(void* const* d_in, const int* in_sizes, int n_in,
                              void* d_out, int out_size, void* d_ws, size_t ws_size,
                              hipStream_t stream) {
  const float* x  = (const float*)d_in[0];
  const float* Wv = (const float*)d_in[5];
  const float* bv = (const float*)d_in[6];
  const float* Wo = (const float*)d_in[7];
  const float* bo = (const float*)d_in[8];
  const float* Wn = (const float*)d_in[9];
  const float* bn = (const float*)d_in[10];
  float* out = (float*)d_out;

  char* ws = (char*)d_ws;
  u16* xb  = (u16*)ws;                             // 8192*4096*2 = 64 MB
  u16* Wnb = (u16*)(ws + (64L << 20));             // 4096*4096*2 = 32 MB
  u16* V   = (u16*)(ws + (96L << 20));             // 8192*64*2   = 1 MB
  u16* Wm  = (u16*)(ws + (97L << 20));             // 4096*64*2   = 512 KB
  float* biasTot = (float*)(ws + (97L << 20) + (512 << 10));  // 16 KB

  k_pre<<<dim3(8960), dim3(256), 0, stream>>>(x, Wv, bv, Wo, bo, Wn, bn,
                                              xb, Wnb, V, Wm, biasTot);
  k_main<<<dim3(2048), dim3(256), 0, stream>>>(xb, Wnb, V, Wm, biasTot, out);
}

// Round 4
// 605.907 us; speedup vs baseline: 1.3285x; 1.3285x over previous
//
#include <hip/hip_runtime.h>
#include <stdint.h>

// Problem (fp32 in / fp32 out): out = relu((x + (x@Wv^T+bv)@Wo^T + bo) @ Wn^T + bn)
//   softmax over a single score == 1 -> q,k path is dead code.
// Reformulated: out = relu(x@Wn^T + v@Wm^T + biasTot)
//   v  = x@Wv^T + bv          [8192 x 64]
//   Wm = Wn @ Wo              [4096 x 64]
//   biasTot = bn + Wn @ bo    [4096]
// Round 4: round-2 structure (best, 666 us); ONLY k_main changed:
//   BK=32 -> BK=64 (barrier-drain amortization), XOR-swizzled LDS slots,
//   V/Wm rank-64 correction = exactly one extra BK=64 iteration.

typedef unsigned short u16;
typedef float f32x4 __attribute__((ext_vector_type(4)));
typedef __bf16 bf16x8 __attribute__((ext_vector_type(8)));
typedef u16 u16x8 __attribute__((ext_vector_type(8)));

__device__ __forceinline__ float b2f(u16 u) {
  union { unsigned int i; float f; } x; x.i = ((unsigned int)u) << 16; return x.f;
}
__device__ __forceinline__ u16 f2b(float f) {  // round-to-nearest-even
  union { float f; unsigned int i; } x; x.f = f;
  unsigned int r = x.i + 0x7FFFu + ((x.i >> 16) & 1u);
  return (u16)(r >> 16);
}

// async global->LDS, 16B per lane; lds base wave-uniform (lane lands at base + lane*16B)
__device__ __forceinline__ void gl_lds16(const u16* g, u16* l) {
#if __has_builtin(__builtin_amdgcn_global_load_lds)
  __builtin_amdgcn_global_load_lds((__attribute__((address_space(1))) void*)g,
                                   (__attribute__((address_space(3))) void*)l, 16, 0, 0);
#else
  int lane = threadIdx.x & 63;
  *(u16x8*)(l + lane * 8) = *(const u16x8*)g;
#endif
}

__device__ __forceinline__ f32x4 mfma16(bf16x8 a, bf16x8 b, f32x4 c) {
  return __builtin_amdgcn_mfma_f32_16x16x32_bf16(a, b, c, 0, 0, 0);
}

// ---------------------------------------------------------------------------
// k_cvt: fp32 -> bf16 for x (33.5M), Wn (16.7M), Wv (262K). 8 floats/thread.
// (identical to round 2)
// ---------------------------------------------------------------------------
#define XCH 4194304L   // 33554432/8
#define WNCH 2097152L  // 16777216/8
__global__ __launch_bounds__(256) void k_cvt(
    const float* __restrict__ x, const float* __restrict__ Wn, const float* __restrict__ Wv,
    u16* __restrict__ xb, u16* __restrict__ Wnb, u16* __restrict__ Wvb) {
  long i = (long)blockIdx.x * 256 + threadIdx.x;
  const float* src; u16* dst; long off;
  if (i < XCH) { src = x; dst = xb; off = i * 8; }
  else if (i < XCH + WNCH) { src = Wn; dst = Wnb; off = (i - XCH) * 8; }
  else { src = Wv; dst = Wvb; off = (i - XCH - WNCH) * 8; }
  f32x4 a = *(const f32x4*)&src[off];
  f32x4 b = *(const f32x4*)&src[off + 4];
  u16x8 o;
#pragma unroll
  for (int e = 0; e < 4; ++e) { o[e] = f2b(a[e]); o[4 + e] = f2b(b[e]); }
  *(u16x8*)&dst[off] = o;
}

// ---------------------------------------------------------------------------
// kT: WoT[a][k] = bf16(Wo[k][a])  (identical to round 2)
// ---------------------------------------------------------------------------
__global__ __launch_bounds__(256) void kT(const float* __restrict__ Wo, u16* __restrict__ WoT) {
  __shared__ __align__(16) u16 t[64 * 72];
  const int b = blockIdx.x;
  const int tid = threadIdx.x;
  {
    int k = tid >> 2, a0 = (tid & 3) * 16;
    const float* src = &Wo[(size_t)(b * 64 + k) * 64 + a0];
#pragma unroll
    for (int q = 0; q < 4; ++q) {
      f32x4 v = *(const f32x4*)&src[q * 4];
#pragma unroll
      for (int e = 0; e < 4; ++e) t[k * 72 + a0 + q * 4 + e] = f2b(v[e]);
    }
  }
  __syncthreads();
  {
    int a = tid >> 2, k0 = (tid & 3) * 16;
    u16x8 o0, o1;
#pragma unroll
    for (int j = 0; j < 8; ++j) o0[j] = t[(k0 + j) * 72 + a];
#pragma unroll
    for (int j = 0; j < 8; ++j) o1[j] = t[(k0 + 8 + j) * 72 + a];
    *(u16x8*)&WoT[(size_t)a * 4096 + b * 64 + k0] = o0;
    *(u16x8*)&WoT[(size_t)a * 4096 + b * 64 + k0 + 8] = o1;
  }
}

// ---------------------------------------------------------------------------
// gemm_n64 (identical to round 2)
// ---------------------------------------------------------------------------
#define PBK 128
__device__ void gemm_n64(const u16* __restrict__ A, const u16* __restrict__ B,
                         u16* __restrict__ C, const float* __restrict__ bias,
                         long m0, u16* lA, u16* lB) {
  const int tid = threadIdx.x;
  const int w = tid >> 6, l = tid & 63;
  f32x4 acc[4];
#pragma unroll
  for (int nt = 0; nt < 4; ++nt) acc[nt] = (f32x4)(0.f);

  for (int k0 = 0; k0 < 4096; k0 += PBK) {
    __syncthreads();
#pragma unroll
    for (int i = 0; i < 4; ++i) {
      int row = w * 16 + i * 4 + (l >> 4);
      int p = (l & 15) ^ (i * 4 + (l >> 4));
      gl_lds16(A + (m0 + row) * (long)4096 + k0 + p * 8, lA + (w * 16 + i * 4) * PBK);
      gl_lds16(B + (long)row * 4096 + k0 + p * 8, lB + (w * 16 + i * 4) * PBK);
    }
    __syncthreads();
#pragma unroll
    for (int kk = 0; kk < 4; ++kk) {
      int slotA = ((kk * 4 + (l >> 4)) ^ (l & 15)) * 8;
      bf16x8 af = *(const bf16x8*)&lA[(w * 16 + (l & 15)) * PBK + slotA];
#pragma unroll
      for (int nt = 0; nt < 4; ++nt) {
        bf16x8 bf = *(const bf16x8*)&lB[(nt * 16 + (l & 15)) * PBK + slotA];
        acc[nt] = mfma16(af, bf, acc[nt]);
      }
    }
  }
#pragma unroll
  for (int nt = 0; nt < 4; ++nt) {
    int col = nt * 16 + (l & 15);
    float bb = bias ? bias[col] : 0.f;
#pragma unroll
    for (int r = 0; r < 4; ++r) {
      long row = m0 + w * 16 + (l >> 4) * 4 + r;
      C[row * 64 + col] = f2b(acc[nt][r] + bb);
    }
  }
}

// ---------------------------------------------------------------------------
// k_prep (identical to round 2)
// ---------------------------------------------------------------------------
__global__ __launch_bounds__(256, 2) void k_prep(
    const u16* __restrict__ xb, const u16* __restrict__ Wvb, const float* __restrict__ bv,
    const u16* __restrict__ Wnb, const u16* __restrict__ WoT,
    const float* __restrict__ bo, const float* __restrict__ bn,
    u16* __restrict__ V, u16* __restrict__ Wm, float* __restrict__ biasTot) {
  __shared__ __align__(16) u16 lA[64 * PBK];
  __shared__ __align__(16) u16 lB[64 * PBK];
  const int bid = blockIdx.x;
  if (bid < 128) {
    gemm_n64(xb, Wvb, V, bv, (long)bid * 64, lA, lB);
  } else if (bid < 192) {
    gemm_n64(Wnb, WoT, Wm, nullptr, (long)(bid - 128) * 64, lA, lB);
  } else {
    const int w = threadIdx.x >> 6, l = threadIdx.x & 63;
    const int n = (bid - 192) * 4 + w;
    float s = 0.f;
#pragma unroll
    for (int j = 0; j < 8; ++j) {
      int off = (j * 64 + l) * 8;
      u16x8 a = *(const u16x8*)&Wnb[(size_t)n * 4096 + off];
      f32x4 c0 = *(const f32x4*)&bo[off];
      f32x4 c1 = *(const f32x4*)&bo[off + 4];
#pragma unroll
      for (int e = 0; e < 4; ++e) s += b2f(a[e]) * c0[e] + b2f(a[4 + e]) * c1[e];
    }
#pragma unroll
    for (int o = 32; o > 0; o >>= 1) s += __shfl_xor(s, o, 64);
    if (l == 0) biasTot[n] = s + bn[n];
  }
}

// ---------------------------------------------------------------------------
// k_main (ROUND-4 CHANGE): BK=64, XOR-swizzled LDS (128B rows), 64 main iters
//   + 1 tail iter (V/Wm, K=64). 128x128 tile, 4 waves 2x2, gl_lds16 staging,
//   fp32 out via per-wave LDS transpose. LDS 32 KB.
// Swizzle: staging lane l covers row i*8+(l>>3), LDS slot l&7, global 16B-slot
//   (l&7)^(l>>3)  => LDS[row][s] holds global slot s^(row&7).
//   Fragment read of global slot g from row r: LDS slot g^(r&7), r&7==l&7.
// ---------------------------------------------------------------------------
__global__ __launch_bounds__(256, 2) void k_main(
    const u16* __restrict__ X, const u16* __restrict__ Wn,
    const u16* __restrict__ V, const u16* __restrict__ Wm,
    const float* __restrict__ biasTot, float* __restrict__ Out) {
  __shared__ __align__(16) u16 smem[2 * 128 * 64];  // 32 KB
  u16* lA = smem;
  u16* lB = smem + 128 * 64;
  const int tid = threadIdx.x;
  const int w = tid >> 6, l = tid & 63;
  const int wRow = (w & 1) * 64, wCol = (w >> 1) * 64;
  const long mBase = (long)(blockIdx.x >> 5) * 128;
  const int nBase = (int)(blockIdx.x & 31) * 128;

  f32x4 acc[4][4];
#pragma unroll
  for (int mt = 0; mt < 4; ++mt)
#pragma unroll
    for (int nt = 0; nt < 4; ++nt) acc[mt][nt] = (f32x4)(0.f);

  const int srow = l >> 3;            // staging sub-row 0..7
  const int sp = ((l & 7) ^ srow) * 8;  // swizzled global 16B-slot (elements)

  for (int kb = 0; kb < 65; ++kb) {
    const u16 *pA, *pB; long lda;
    if (kb < 64) { pA = X + (long)kb * 64; pB = Wn + (long)kb * 64; lda = 4096; }
    else         { pA = V;                 pB = Wm;                 lda = 64;  }
    __syncthreads();
#pragma unroll
    for (int i = 0; i < 4; ++i) {
      int row = w * 32 + i * 8 + srow;
      gl_lds16(pA + (mBase + row) * lda + sp, lA + (w * 32 + i * 8) * 64);
      gl_lds16(pB + (long)(nBase + row) * lda + sp, lB + (w * 32 + i * 8) * 64);
    }
    __syncthreads();
#pragma unroll
    for (int kk = 0; kk < 2; ++kk) {
      int slot = ((kk * 4 + (l >> 4)) ^ (l & 7)) * 8;
      bf16x8 af[4], bfr[4];
#pragma unroll
      for (int mt = 0; mt < 4; ++mt)
        af[mt] = *(const bf16x8*)&lA[(wRow + mt * 16 + (l & 15)) * 64 + slot];
#pragma unroll
      for (int nt = 0; nt < 4; ++nt)
        bfr[nt] = *(const bf16x8*)&lB[(wCol + nt * 16 + (l & 15)) * 64 + slot];
#pragma unroll
      for (int mt = 0; mt < 4; ++mt)
#pragma unroll
        for (int nt = 0; nt < 4; ++nt) acc[mt][nt] = mfma16(af[mt], bfr[nt], acc[mt][nt]);
    }
  }

  // epilogue: bias + relu, fp32; per-wave LDS transpose (4 KB/wave), dwordx4 stores
  __syncthreads();
  float* eb = ((float*)smem) + w * 1024;
#pragma unroll
  for (int mt = 0; mt < 4; ++mt) {
#pragma unroll
    for (int nt = 0; nt < 4; ++nt) {
      float bt = biasTot[nBase + wCol + nt * 16 + (l & 15)];
#pragma unroll
      for (int r = 0; r < 4; ++r) {
        float val = acc[mt][nt][r] + bt;
        eb[((l >> 4) * 4 + r) * 64 + nt * 16 + (l & 15)] = fmaxf(val, 0.f);
      }
    }
    int rr = l >> 2, c0 = (l & 3) * 16;
    long grow = mBase + wRow + mt * 16 + rr;
    int gcol = nBase + wCol + c0;
    f32x4 o0 = *(const f32x4*)&eb[rr * 64 + c0];
    f32x4 o1 = *(const f32x4*)&eb[rr * 64 + c0 + 4];
    f32x4 o2 = *(const f32x4*)&eb[rr * 64 + c0 + 8];
    f32x4 o3 = *(const f32x4*)&eb[rr * 64 + c0 + 12];
    *(f32x4*)&Out[grow * 4096 + gcol] = o0;
    *(f32x4*)&Out[grow * 4096 + gcol + 4] = o1;
    *(f32x4*)&Out[grow * 4096 + gcol + 8] = o2;
    *(f32x4*)&Out[grow * 4096 + gcol + 12] = o3;
  }
}

// ---------------------------------------------------------------------------
extern "C" void kernel_launch(void* const* d_in, const int* in_sizes, int n_in,
                              void* d_out, int out_size, void* d_ws, size_t ws_size,
                              hipStream_t stream) {
  const float* x  = (const float*)d_in[0];
  const float* Wv = (const float*)d_in[5];
  const float* bv = (const float*)d_in[6];
  const float* Wo = (const float*)d_in[7];
  const float* bo = (const float*)d_in[8];
  const float* Wn = (const float*)d_in[9];
  const float* bn = (const float*)d_in[10];
  float* out = (float*)d_out;

  char* ws = (char*)d_ws;
  u16* xb  = (u16*)ws;                             // 8192*4096*2 = 64 MB
  u16* Wnb = (u16*)(ws + (64L << 20));             // 4096*4096*2 = 32 MB
  u16* Wvb = (u16*)(ws + (96L << 20));             // 64*4096*2   = 512 KB
  u16* WoT = (u16*)(ws + (96L << 20) + (512 << 10));   // 512 KB
  u16* V   = (u16*)(ws + (97L << 20));             // 8192*64*2   = 1 MB
  u16* Wm  = (u16*)(ws + (98L << 20));             // 4096*64*2   = 512 KB
  float* biasTot = (float*)(ws + (98L << 20) + (512 << 10));  // 16 KB

  k_cvt<<<dim3(24704), dim3(256), 0, stream>>>(x, Wn, Wv, xb, Wnb, Wvb);
  kT<<<dim3(64), dim3(256), 0, stream>>>(Wo, WoT);
  k_prep<<<dim3(1216), dim3(256), 0, stream>>>(xb, Wvb, bv, Wnb, WoT, bo, bn, V, Wm, biasTot);
  k_main<<<dim3(2048), dim3(256), 0, stream>>>(xb, Wnb, V, Wm, biasTot, out);
}